// Round 7
// baseline (409.543 us; speedup 1.0000x reference)
//
#include <hip/hip_runtime.h>

// Problem constants (fixed by the reference)
#define NN 50000
#define EE 1600000
#define FIN 512
#define HH 128

#define CAP 80          // bucket capacity per dst (Poisson(32); P(deg>80) ~ 1e-11)
#define OVF_CAP 64512   // overflow list capacity (per-node CAP net, ~never used)

// counting-sort parameters
#define GROUP 128                        // nodes per bin
#define NB ((NN + GROUP - 1) / GROUP)    // 391 bins
#define NBLK 256                         // edge-chunk blocks
#define EPB (EE / NBLK)                  // 6250 edges per block (exact)

typedef short s16x8 __attribute__((ext_vector_type(8)));
typedef float f32x4 __attribute__((ext_vector_type(4)));

static __device__ inline unsigned short f2bf(float f) {
    // fp32 -> bf16 bits, round-to-nearest-even
    unsigned u = __float_as_uint(f);
    unsigned r = (u + 0x7fffu + ((u >> 16) & 1u)) >> 16;
    return (unsigned short)r;
}

static __device__ inline float blo(unsigned u) { return __uint_as_float(u << 16); }
static __device__ inline float bhi(unsigned u) { return __uint_as_float(u & 0xffff0000u); }

static __device__ inline float deg2dinv(float d) { return (d > 0.0f) ? rsqrtf(d) : 0.0f; }

// ---------------- build kernels (atomic-free counting sort by bin) ----------------

// Pass 1: per-(block,bin) histogram via LDS atomics (block-local, cheap).
__global__ __launch_bounds__(256) void hist_kernel(const int* __restrict__ dst,
                                                   int* __restrict__ hist) {
    __shared__ int h[NB];
    const int tid = threadIdx.x;
    for (int i = tid; i < NB; i += 256) h[i] = 0;
    __syncthreads();
    const int base = blockIdx.x * EPB;
    for (int i = tid; i < EPB; i += 256)
        atomicAdd(&h[dst[base + i] >> 7], 1);
    __syncthreads();
    for (int i = tid; i < NB; i += 256) hist[blockIdx.x * NB + i] = h[i];
}

// Pass 2: one wave per bin — exclusive scan of hist[*][bin] over the 256 blocks.
// binBase via atomic cursor (bin placement order is irrelevant; each bin's range
// [binBase, binBase+total) is exact) -> kills the separate bin_base kernel.
__global__ __launch_bounds__(64) void scan_bins(const int* __restrict__ hist,
                                                int* __restrict__ off,
                                                int* __restrict__ binTotal,
                                                int* __restrict__ binBase,
                                                int* __restrict__ cursor) {
    const int bin = blockIdx.x;
    const int lane = threadIdx.x;
    int v[4];
    int s = 0;
#pragma unroll
    for (int i = 0; i < 4; ++i) { v[i] = hist[(lane * 4 + i) * NB + bin]; s += v[i]; }
    int incl = s;
#pragma unroll
    for (int d = 1; d < 64; d <<= 1) {
        int t = __shfl_up(incl, d, 64);
        if (lane >= d) incl += t;
    }
    int run = incl - s;   // exclusive prefix of this lane's 4 blocks
#pragma unroll
    for (int i = 0; i < 4; ++i) { off[(lane * 4 + i) * NB + bin] = run; run += v[i]; }
    if (lane == 63) {
        binTotal[bin] = incl;
        binBase[bin] = atomicAdd(cursor, incl);
    }
}

// Pass 3: deterministic placement. LDS cursors seeded from scanned offsets —
// zero global atomics in the edge loop; every bins[] slot written exactly once.
// Entry: x = src | (dstLocal<<16)  (src < 2^16, dstLocal < 128), y = w bits.
__global__ __launch_bounds__(256) void place_kernel(const int* __restrict__ src,
                                                    const int* __restrict__ dst,
                                                    const float* __restrict__ w,
                                                    const int* __restrict__ off,
                                                    const int* __restrict__ binBase,
                                                    int2* __restrict__ bins) {
    __shared__ int cur[NB];
    const int tid = threadIdx.x;
    for (int i = tid; i < NB; i += 256)
        cur[i] = binBase[i] + off[blockIdx.x * NB + i];
    __syncthreads();
    const int base = blockIdx.x * EPB;
    for (int i = tid; i < EPB; i += 256) {
        int e = base + i;
        int s = src[e], d = dst[e];
        float we = w[e];
        int pos = atomicAdd(&cur[d >> 7], 1);
        bins[pos] = make_int2(s | ((d & 127) << 16), __float_as_int(we));
    }
}

// Pass 4: one block per bin. Scatter entries into per-node buckets (80KB window
// per bin, L2-resident). Per-node positions and weight sums via LDS atomics.
// lw counts EVERY entry's weight (even CAP-overflow ones) -> deg complete here,
// ovf_deg kernel eliminated.
__global__ __launch_bounds__(512) void bucket_build(const int* __restrict__ binBase,
                                                    const int* __restrict__ binTotal,
                                                    const int2* __restrict__ bins,
                                                    int* __restrict__ cnt,
                                                    int2* __restrict__ bucket,
                                                    float* __restrict__ deg,
                                                    int* __restrict__ ovf_cnt,
                                                    int4* __restrict__ ovf) {
    __shared__ int lcnt[GROUP];
    __shared__ float lw[GROUP];
    const int b = blockIdx.x;
    const int tid = threadIdx.x;
    if (tid < GROUP) { lcnt[tid] = 0; lw[tid] = 0.0f; }
    __syncthreads();
    const int base = b * GROUP;
    const int start = binBase[b];
    const int n = binTotal[b];
    for (int i = tid; i < n; i += 512) {
        int2 en = bins[start + i];
        int sr = en.x & 0xffff;
        int dl = (en.x >> 16) & 127;
        atomicAdd(&lw[dl], __int_as_float(en.y));      // deg: every edge counted
        int pos = atomicAdd(&lcnt[dl], 1);
        if (pos < CAP) {
            bucket[(size_t)(base + dl) * CAP + pos] = make_int2(sr, en.y);
        } else {
            // node exceeded CAP: divert neighbor contribution to overflow net
            int o = atomicAdd(ovf_cnt, 1);
            if (o < OVF_CAP) ovf[o] = make_int4(sr, base + dl, en.y, 0);
        }
    }
    __syncthreads();
    for (int i = tid; i < GROUP; i += 512) {
        int node = base + i;
        if (node < NN) {
            cnt[node] = lcnt[i];                 // raw; consumers do min(cnt, CAP)
            deg[node] = 1.0f + lw[i];            // self-loop + ALL edge weights
        }
    }
}

// ---------------- GEMM1: h2[M,128](bf16) = dinv .* (x[M,512](f32) @ Wc[512,128](f32)) ----
// Memory-bound (57 FLOP/B). BM=64 -> 782 blocks (vs 391) fixes grid starvation
// (~24 waves/CU vs 12). 512 threads (8 waves, 4x2); 2-deep register prefetch
// hides HBM latency across two K-iterations. dinv = rsqrt(deg) inline.

__global__ __launch_bounds__(512) void gemm1_kernel(const float* __restrict__ A,
                                                    const float* __restrict__ B,
                                                    const float* __restrict__ deg,
                                                    unsigned short* __restrict__ h2,
                                                    int M) {
    __shared__ short As[64][40];    // [m][k], pad to 40 (80B rows)
    __shared__ short Bs[128][40];   // [n][k]
    const int bm = blockIdx.x * 64;
    const int tid = threadIdx.x;
    const int wave = tid >> 6, lane = tid & 63;
    const int wm = wave >> 1, wn = wave & 1;        // 4x2 wave grid: 16-row x 64-col per wave
    const int mlane = lane & 15, quad = lane >> 4;

    // staging geometry: A = 512 float4 tasks -> 1/thread; B = 512 (n,kg) tasks -> 1/thread
    const int ar = tid >> 3, akq = tid & 7;          // A row 0..63, k-quad 0..7
    const int bn = tid & 127, bkg = tid >> 7;        // B col bn, k-group bkg (0..3)

    f32x4 acc[4];
#pragma unroll
    for (int j = 0; j < 4; ++j) acc[j] = (f32x4){0.f, 0.f, 0.f, 0.f};

    float4 pa0, pa1;
    float pb0[8], pb1[8];

    auto loadT = [&](float4& pa, float (&pb)[8], int k0) {
        int grow = bm + ar;
        pa = make_float4(0.f, 0.f, 0.f, 0.f);
        if (grow < M) pa = *(const float4*)(A + (size_t)grow * FIN + k0 + akq * 4);
#pragma unroll
        for (int j = 0; j < 8; ++j)
            pb[j] = B[(size_t)(k0 + bkg * 8 + j) * HH + bn];
    };
    auto storeT = [&](float4& pa, float (&pb)[8]) {
        ushort4 b;
        b.x = f2bf(pa.x); b.y = f2bf(pa.y); b.z = f2bf(pa.z); b.w = f2bf(pa.w);
        *(ushort4*)&As[ar][akq * 4] = b;
        unsigned short tmp[8];
#pragma unroll
        for (int j = 0; j < 8; ++j) tmp[j] = f2bf(pb[j]);
        *(s16x8*)&Bs[bn][bkg * 8] = *(s16x8*)tmp;
    };
    auto mmaT = [&]() {
        s16x8 af, bfr[4];
        af = *(const s16x8*)&As[wm * 16 + mlane][quad * 8];
#pragma unroll
        for (int nt = 0; nt < 4; ++nt)
            bfr[nt] = *(const s16x8*)&Bs[wn * 64 + nt * 16 + mlane][quad * 8];
#pragma unroll
        for (int nt = 0; nt < 4; ++nt)
            acc[nt] = __builtin_amdgcn_mfma_f32_16x16x32_bf16(af, bfr[nt], acc[nt], 0, 0, 0);
    };

    // 2-deep pipeline over 16 K-steps (named regs -> no dynamic indexing/scratch)
    loadT(pa0, pb0, 0);
    loadT(pa1, pb1, 32);
    for (int kk = 0; kk < 16; kk += 2) {
        storeT(pa0, pb0);               // waits only on loads issued 2 iters ago
        __syncthreads();
        if (kk + 2 < 16) loadT(pa0, pb0, (kk + 2) * 32);
        mmaT();
        __syncthreads();
        storeT(pa1, pb1);
        __syncthreads();
        if (kk + 3 < 16) loadT(pa1, pb1, (kk + 3) * 32);
        mmaT();
        __syncthreads();
    }

    // epilogue: D[row=quad*4+r][col=lane&15] per frag; scale by dinv(deg), store bf16
#pragma unroll
    for (int r = 0; r < 4; ++r) {
        int row = bm + wm * 16 + quad * 4 + r;
        if (row < M) {
            float sc = deg2dinv(deg[row]);
#pragma unroll
            for (int nt = 0; nt < 4; ++nt) {
                int col = wn * 64 + nt * 16 + mlane;
                h2[(size_t)row * HH + col] = f2bf(acc[nt][r] * sc);
            }
        }
    }
}

// ---------------- aggregation, feature-quartered (bf16 in / bf16 out) ----------------
// agg[d] = bf16( b_conv + dinv[d] * (h2[d] + sum_e w_e * h2[src_e]) )
// 4 sequential passes over 32-feature quarters: each pass's gather table slice is
// 50000 x 64B = 3.2MB -> fits every XCD's 4MiB L2 (the full 12.8MB table did not;
// R3 showed 156MB FETCH = L3 round-trips). A 16-lane group owns one node; each
// gather is exactly one 64B line (u=0..15 within the quarter). 8 edges in flight
// per group for MLP.

__global__ __launch_bounds__(256) void agg_pass(const unsigned int* __restrict__ h2u,
                                                const int* __restrict__ cnt,
                                                const int2* __restrict__ bucket,
                                                const float* __restrict__ deg,
                                                const float* __restrict__ b_conv,
                                                const int* __restrict__ ovf_cnt,
                                                const int4* __restrict__ ovf,
                                                unsigned int* __restrict__ aggu,
                                                int qb, int n) {    // qb = quarter*16 (uint offset)
    const int tid = threadIdx.x;
    const int wave = tid >> 6, lane = tid & 63;
    const int g = lane >> 4, u = lane & 15;
    const int node = blockIdx.x * 16 + wave * 4 + g;
    const bool valid = node < n;
    const int c = valid ? min(cnt[node], CAP) : 0;
    const int2* e = bucket + (size_t)(valid ? node : 0) * CAP;

    float a0 = 0.f, a1 = 0.f, b0 = 0.f, b1 = 0.f;
    for (int j = 0; j < c; j += 8) {
        // clamped indices keep addresses valid; weights zeroed past c
        int j1 = min(j + 1, c - 1), j2 = min(j + 2, c - 1), j3 = min(j + 3, c - 1);
        int j4 = min(j + 4, c - 1), j5 = min(j + 5, c - 1), j6 = min(j + 6, c - 1);
        int j7 = min(j + 7, c - 1);
        int2 p0 = e[j],  p1 = e[j1], p2 = e[j2], p3 = e[j3];
        int2 p4 = e[j4], p5 = e[j5], p6 = e[j6], p7 = e[j7];
        unsigned u0 = h2u[(size_t)p0.x * 64 + qb + u];
        unsigned u1 = h2u[(size_t)p1.x * 64 + qb + u];
        unsigned u2 = h2u[(size_t)p2.x * 64 + qb + u];
        unsigned u3 = h2u[(size_t)p3.x * 64 + qb + u];
        unsigned u4 = h2u[(size_t)p4.x * 64 + qb + u];
        unsigned u5 = h2u[(size_t)p5.x * 64 + qb + u];
        unsigned u6 = h2u[(size_t)p6.x * 64 + qb + u];
        unsigned u7 = h2u[(size_t)p7.x * 64 + qb + u];
        float w0 = __int_as_float(p0.y);
        float w1 = (j + 1 < c) ? __int_as_float(p1.y) : 0.f;
        float w2 = (j + 2 < c) ? __int_as_float(p2.y) : 0.f;
        float w3 = (j + 3 < c) ? __int_as_float(p3.y) : 0.f;
        float w4 = (j + 4 < c) ? __int_as_float(p4.y) : 0.f;
        float w5 = (j + 5 < c) ? __int_as_float(p5.y) : 0.f;
        float w6 = (j + 6 < c) ? __int_as_float(p6.y) : 0.f;
        float w7 = (j + 7 < c) ? __int_as_float(p7.y) : 0.f;
        a0 += w0 * blo(u0); a1 += w0 * bhi(u0);
        b0 += w1 * blo(u1); b1 += w1 * bhi(u1);
        a0 += w2 * blo(u2); a1 += w2 * bhi(u2);
        b0 += w3 * blo(u3); b1 += w3 * bhi(u3);
        a0 += w4 * blo(u4); a1 += w4 * bhi(u4);
        b0 += w5 * blo(u5); b1 += w5 * bhi(u5);
        a0 += w6 * blo(u6); a1 += w6 * bhi(u6);
        b0 += w7 * blo(u7); b1 += w7 * bhi(u7);
    }

    if (valid) {
        // overflow net (ovf_n is ~always 0)
        int ovf_n = min(*ovf_cnt, OVF_CAP);
        for (int i = 0; i < ovf_n; ++i) {
            int4 v = ovf[i];
            if (v.y == node) {
                float w = __int_as_float(v.z);
                unsigned uv = h2u[(size_t)v.x * 64 + qb + u];
                a0 += w * blo(uv); a1 += w * bhi(uv);
            }
        }
        unsigned self = h2u[(size_t)node * 64 + qb + u];
        float di = deg2dinv(deg[node]);
        float2 bc = *(const float2*)&b_conv[(qb + u) * 2];
        float v0 = bc.x + di * (blo(self) + a0 + b0);
        float v1 = bc.y + di * (bhi(self) + a1 + b1);
        aggu[(size_t)node * 64 + qb + u] = (unsigned)f2bf(v0) | ((unsigned)f2bf(v1) << 16);
    }
}

// ---------------- GEMM2: out[M,512](f32) = agg[M,128](bf16) @ Wl[128,512](f32) + b_lin ----
// 512 threads (8 waves, 4x2), 2-deep register prefetch over the 4 K-steps.

__global__ __launch_bounds__(512) void gemm2_kernel(const unsigned short* __restrict__ A,
                                                    const float* __restrict__ B,
                                                    const float* __restrict__ bias,
                                                    float* __restrict__ C,
                                                    int M) {
    __shared__ short As[128][40];
    __shared__ short Bs[128][40];
    const int bm = blockIdx.x * 128;
    const int bnb = blockIdx.y * 128;
    const int tid = threadIdx.x;
    const int wave = tid >> 6, lane = tid & 63;
    const int wm = wave >> 1, wn = wave & 1;        // 4x2 wave grid: 32-row x 64-col per wave
    const int mlane = lane & 15, quad = lane >> 4;

    // staging geometry: A = 512 16B tasks -> 1/thread; B = 512 (n,kg) tasks -> 1/thread
    const int ar = tid >> 2, ach = tid & 3;          // A row, 16B chunk
    const int bn = tid & 127, bkg = tid >> 7;        // B col, k-group (0..3)

    f32x4 acc[2][4];
#pragma unroll
    for (int i = 0; i < 2; ++i)
#pragma unroll
        for (int j = 0; j < 4; ++j) acc[i][j] = (f32x4){0.f, 0.f, 0.f, 0.f};

    s16x8 pa0, pa1;
    float pb0[8], pb1[8];

    auto loadT = [&](s16x8& pa, float (&pb)[8], int k0) {
        int grow = bm + ar;
        pa = (s16x8){0, 0, 0, 0, 0, 0, 0, 0};
        if (grow < M) pa = *(const s16x8*)(A + (size_t)grow * HH + k0 + ach * 8);
#pragma unroll
        for (int j = 0; j < 8; ++j)
            pb[j] = B[(size_t)(k0 + bkg * 8 + j) * FIN + bnb + bn];
    };
    auto storeT = [&](s16x8& pa, float (&pb)[8]) {
        *(s16x8*)&As[ar][ach * 8] = pa;
        unsigned short tmp[8];
#pragma unroll
        for (int j = 0; j < 8; ++j) tmp[j] = f2bf(pb[j]);
        *(s16x8*)&Bs[bn][bkg * 8] = *(s16x8*)tmp;
    };
    auto mmaT = [&]() {
        s16x8 af[2], bfr[4];
#pragma unroll
        for (int mt = 0; mt < 2; ++mt)
            af[mt] = *(const s16x8*)&As[wm * 32 + mt * 16 + mlane][quad * 8];
#pragma unroll
        for (int nt = 0; nt < 4; ++nt)
            bfr[nt] = *(const s16x8*)&Bs[wn * 64 + nt * 16 + mlane][quad * 8];
#pragma unroll
        for (int mt = 0; mt < 2; ++mt)
#pragma unroll
            for (int nt = 0; nt < 4; ++nt)
                acc[mt][nt] = __builtin_amdgcn_mfma_f32_16x16x32_bf16(af[mt], bfr[nt], acc[mt][nt], 0, 0, 0);
    };

    // 2-deep pipeline over 4 K-steps
    loadT(pa0, pb0, 0);
    loadT(pa1, pb1, 32);
    for (int kk = 0; kk < 4; kk += 2) {
        storeT(pa0, pb0);
        __syncthreads();
        if (kk + 2 < 4) loadT(pa0, pb0, (kk + 2) * 32);
        mmaT();
        __syncthreads();
        storeT(pa1, pb1);
        __syncthreads();
        if (kk + 3 < 4) loadT(pa1, pb1, (kk + 3) * 32);
        mmaT();
        __syncthreads();
    }

#pragma unroll
    for (int mt = 0; mt < 2; ++mt) {
#pragma unroll
        for (int r = 0; r < 4; ++r) {
            int row = bm + wm * 32 + mt * 16 + quad * 4 + r;
            if (row < M) {
#pragma unroll
                for (int nt = 0; nt < 4; ++nt) {
                    int col = bnb + wn * 64 + nt * 16 + mlane;
                    C[(size_t)row * FIN + col] = acc[mt][nt][r] + bias[col];
                }
            }
        }
    }
}

// ---------------- launch ----------------

extern "C" void kernel_launch(void* const* d_in, const int* in_sizes, int n_in,
                              void* d_out, int out_size, void* d_ws, size_t ws_size,
                              hipStream_t stream) {
    const float* x      = (const float*)d_in[0];
    const int*   ei     = (const int*)d_in[1];
    const float* ew     = (const float*)d_in[2];
    const float* W_conv = (const float*)d_in[3];
    const float* b_conv = (const float*)d_in[4];
    const float* W_lin  = (const float*)d_in[5];
    const float* b_lin  = (const float*)d_in[6];
    float* out = (float*)d_out;

    const int* src = ei;
    const int* dst = ei + EE;

    // workspace layout (bytes, 256-aligned):
    char* ws = (char*)d_ws;
    int*            cnt      = (int*)           (ws + 0);          //   200,704
    float*          deg      = (float*)         (ws + 200704);     //   200,704
    int*            ovf_cnt  = (int*)           (ws + 602112);     //   4 (block of 256)
    int*            cursor   = (int*)           (ws + 602116);     //   4 (same block)
    int*            binTotal = (int*)           (ws + 602368);     //     1,792
    int*            binBase  = (int*)           (ws + 604160);     //     1,792
    int4*           ovf      = (int4*)          (ws + 605952);     // 1,032,192 (64512 entries) -> 1,638,144
    int2*           bucket   = (int2*)          (ws + 1650944);    // 32,000,000 -> 33,650,944
    unsigned short* h2       = (unsigned short*)(ws + 33650944);   // 12,800,000
    unsigned short* agg      = (unsigned short*)(ws + 46450944);   // 12,800,000
    // end: 59,250,944 bytes (unchanged footprint)

    // hist/off ALIAS the bucket region (dead until bucket_build writes bucket):
    int*            hist     = (int*)           (ws + 1650944);    //   400,640 (256*391*4)
    int*            off      = (int*)           (ws + 2051584);    //   400,640
    // bins ALIASES h2 (dead until gemm1): 1.6M * 8B = 12,800,000 exactly
    int2*           bins     = (int2*)          (ws + 33650944);

    hipMemsetAsync(ovf_cnt, 0, 2 * sizeof(int), stream);   // ovf_cnt + cursor

    // build: atomic-free counting sort by bin, then per-bin bucket build (LDS atomics)
    hist_kernel<<<NBLK, 256, 0, stream>>>(dst, hist);
    scan_bins<<<NB, 64, 0, stream>>>(hist, off, binTotal, binBase, cursor);
    place_kernel<<<NBLK, 256, 0, stream>>>(src, dst, ew, off, binBase, bins);
    bucket_build<<<NB, 512, 0, stream>>>(binBase, binTotal, bins, cnt, bucket, deg, ovf_cnt, ovf);

    // GEMM1: h2 = bf16(dinv .* (x @ W_conv)), dinv = rsqrt(deg) inline
    gemm1_kernel<<<dim3((NN + 63) / 64, 1), 512, 0, stream>>>(x, W_conv, deg, h2, NN);

    // aggregation: 4 feature-quarter passes (each slice L2-resident per XCD)
    const int agg_grid = (NN + 15) / 16;
    for (int q = 0; q < 4; ++q)
        agg_pass<<<agg_grid, 256, 0, stream>>>((const unsigned int*)h2, cnt, bucket, deg, b_conv,
                                               ovf_cnt, ovf, (unsigned int*)agg, q * 16, NN);

    // GEMM2: out = agg @ W_lin + b_lin
    gemm2_kernel<<<dim3((NN + 127) / 128, FIN / 128), 512, 0, stream>>>(agg, W_lin, b_lin, out, NN);
}

// Round 8
// 348.302 us; speedup vs baseline: 1.1758x; 1.1758x over previous
//
#include <hip/hip_runtime.h>

// Problem constants (fixed by the reference)
#define NN 50000
#define EE 1600000
#define FIN 512
#define HH 128

#define CAP 80          // bucket capacity per dst (Poisson(32); P(deg>80) ~ 1e-11)
#define OVF_CAP 64512   // overflow list capacity (per-node CAP net, ~never used)

// counting-sort parameters
#define GROUP 128                        // nodes per bin
#define NB ((NN + GROUP - 1) / GROUP)    // 391 bins
#define NBLK 256                         // edge-chunk blocks
#define EPB (EE / NBLK)                  // 6250 edges per block (exact)

typedef short s16x8 __attribute__((ext_vector_type(8)));
typedef float f32x4 __attribute__((ext_vector_type(4)));

static __device__ inline unsigned short f2bf(float f) {
    // fp32 -> bf16 bits, round-to-nearest-even
    unsigned u = __float_as_uint(f);
    unsigned r = (u + 0x7fffu + ((u >> 16) & 1u)) >> 16;
    return (unsigned short)r;
}

static __device__ inline float blo(unsigned u) { return __uint_as_float(u << 16); }
static __device__ inline float bhi(unsigned u) { return __uint_as_float(u & 0xffff0000u); }

static __device__ inline float deg2dinv(float d) { return (d > 0.0f) ? rsqrtf(d) : 0.0f; }

// ---------------- build kernels (atomic-free counting sort by bin) ----------------

// Pass 1: per-(block,bin) histogram via LDS atomics (block-local, cheap).
__global__ __launch_bounds__(256) void hist_kernel(const int* __restrict__ dst,
                                                   int* __restrict__ hist) {
    __shared__ int h[NB];
    const int tid = threadIdx.x;
    for (int i = tid; i < NB; i += 256) h[i] = 0;
    __syncthreads();
    const int base = blockIdx.x * EPB;
    for (int i = tid; i < EPB; i += 256)
        atomicAdd(&h[dst[base + i] >> 7], 1);
    __syncthreads();
    for (int i = tid; i < NB; i += 256) hist[blockIdx.x * NB + i] = h[i];
}

// Pass 2: one wave per bin — exclusive scan of hist[*][bin] over the 256 blocks.
// binBase via atomic cursor (bin placement order is irrelevant; each bin's range
// [binBase, binBase+total) is exact) -> no separate bin_base kernel.
__global__ __launch_bounds__(64) void scan_bins(const int* __restrict__ hist,
                                                int* __restrict__ off,
                                                int* __restrict__ binTotal,
                                                int* __restrict__ binBase,
                                                int* __restrict__ cursor) {
    const int bin = blockIdx.x;
    const int lane = threadIdx.x;
    int v[4];
    int s = 0;
#pragma unroll
    for (int i = 0; i < 4; ++i) { v[i] = hist[(lane * 4 + i) * NB + bin]; s += v[i]; }
    int incl = s;
#pragma unroll
    for (int d = 1; d < 64; d <<= 1) {
        int t = __shfl_up(incl, d, 64);
        if (lane >= d) incl += t;
    }
    int run = incl - s;   // exclusive prefix of this lane's 4 blocks
#pragma unroll
    for (int i = 0; i < 4; ++i) { off[(lane * 4 + i) * NB + bin] = run; run += v[i]; }
    if (lane == 63) {
        binTotal[bin] = incl;
        binBase[bin] = atomicAdd(cursor, incl);
    }
}

// Pass 3: deterministic placement. LDS cursors seeded from scanned offsets —
// zero global atomics in the edge loop; every bins[] slot written exactly once.
// Entry: x = src | (dstLocal<<16)  (src < 2^16, dstLocal < 128), y = w bits.
__global__ __launch_bounds__(256) void place_kernel(const int* __restrict__ src,
                                                    const int* __restrict__ dst,
                                                    const float* __restrict__ w,
                                                    const int* __restrict__ off,
                                                    const int* __restrict__ binBase,
                                                    int2* __restrict__ bins) {
    __shared__ int cur[NB];
    const int tid = threadIdx.x;
    for (int i = tid; i < NB; i += 256)
        cur[i] = binBase[i] + off[blockIdx.x * NB + i];
    __syncthreads();
    const int base = blockIdx.x * EPB;
    for (int i = tid; i < EPB; i += 256) {
        int e = base + i;
        int s = src[e], d = dst[e];
        float we = w[e];
        int pos = atomicAdd(&cur[d >> 7], 1);
        bins[pos] = make_int2(s | ((d & 127) << 16), __float_as_int(we));
    }
}

// Pass 4: one block per bin. Scatter entries into per-node buckets (80KB window
// per bin, L2-resident). Per-node positions and weight sums via LDS atomics.
// lw counts EVERY entry's weight (even CAP-overflow ones) -> deg complete here,
// no separate ovf_deg kernel.
__global__ __launch_bounds__(512) void bucket_build(const int* __restrict__ binBase,
                                                    const int* __restrict__ binTotal,
                                                    const int2* __restrict__ bins,
                                                    int* __restrict__ cnt,
                                                    int2* __restrict__ bucket,
                                                    float* __restrict__ deg,
                                                    int* __restrict__ ovf_cnt,
                                                    int4* __restrict__ ovf) {
    __shared__ int lcnt[GROUP];
    __shared__ float lw[GROUP];
    const int b = blockIdx.x;
    const int tid = threadIdx.x;
    if (tid < GROUP) { lcnt[tid] = 0; lw[tid] = 0.0f; }
    __syncthreads();
    const int base = b * GROUP;
    const int start = binBase[b];
    const int n = binTotal[b];
    for (int i = tid; i < n; i += 512) {
        int2 en = bins[start + i];
        int sr = en.x & 0xffff;
        int dl = (en.x >> 16) & 127;
        atomicAdd(&lw[dl], __int_as_float(en.y));      // deg: every edge counted
        int pos = atomicAdd(&lcnt[dl], 1);
        if (pos < CAP) {
            bucket[(size_t)(base + dl) * CAP + pos] = make_int2(sr, en.y);
        } else {
            // node exceeded CAP: divert neighbor contribution to overflow net
            int o = atomicAdd(ovf_cnt, 1);
            if (o < OVF_CAP) ovf[o] = make_int4(sr, base + dl, en.y, 0);
        }
    }
    __syncthreads();
    for (int i = tid; i < GROUP; i += 512) {
        int node = base + i;
        if (node < NN) {
            cnt[node] = lcnt[i];                 // raw; consumers do min(cnt, CAP)
            deg[node] = 1.0f + lw[i];            // self-loop + ALL edge weights
        }
    }
}

// ---------------- GEMM1: h2[M,128](bf16) = dinv .* (x[M,512](f32) @ Wc[512,128](f32)) ----
// Memory-bound (57 FLOP/B). 512 threads (8 waves, 4x2); 2-deep register prefetch
// (issue loads for k+2 during MFMA of k, write-late after the barrier) hides HBM
// latency across two K-iterations. dinv computed inline from deg.
// [R7 lesson: BM=64 split regressed — BM=128 retained.]

__global__ __launch_bounds__(512) void gemm1_kernel(const float* __restrict__ A,
                                                    const float* __restrict__ B,
                                                    const float* __restrict__ deg,
                                                    unsigned short* __restrict__ h2,
                                                    int M) {
    __shared__ short As[128][40];   // [m][k], pad to 40 (80B rows)
    __shared__ short Bs[128][40];   // [n][k]
    const int bm = blockIdx.x * 128;
    const int tid = threadIdx.x;
    const int wave = tid >> 6, lane = tid & 63;
    const int wm = wave >> 1, wn = wave & 1;        // 4x2 wave grid: 32-row x 64-col per wave
    const int mlane = lane & 15, quad = lane >> 4;

    // staging geometry: A = 1024 float4 tasks -> 2/thread; B = 512 (n,kg) tasks -> 1/thread
    const int ar = tid >> 3, akq = tid & 7;          // A rows ar and ar+64
    const int bn = tid & 127, bkg = tid >> 7;        // B col bn, k-group bkg (0..3)

    f32x4 acc[2][4];
#pragma unroll
    for (int i = 0; i < 2; ++i)
#pragma unroll
        for (int j = 0; j < 4; ++j) acc[i][j] = (f32x4){0.f, 0.f, 0.f, 0.f};

    float4 pa0[2], pa1[2];
    float pb0[8], pb1[8];

    auto loadT = [&](float4 (&pa)[2], float (&pb)[8], int k0) {
#pragma unroll
        for (int i = 0; i < 2; ++i) {
            int grow = bm + ar + i * 64;
            pa[i] = make_float4(0.f, 0.f, 0.f, 0.f);
            if (grow < M) pa[i] = *(const float4*)(A + (size_t)grow * FIN + k0 + akq * 4);
        }
#pragma unroll
        for (int j = 0; j < 8; ++j)
            pb[j] = B[(size_t)(k0 + bkg * 8 + j) * HH + bn];
    };
    auto storeT = [&](float4 (&pa)[2], float (&pb)[8]) {
#pragma unroll
        for (int i = 0; i < 2; ++i) {
            ushort4 b;
            b.x = f2bf(pa[i].x); b.y = f2bf(pa[i].y); b.z = f2bf(pa[i].z); b.w = f2bf(pa[i].w);
            *(ushort4*)&As[ar + i * 64][akq * 4] = b;
        }
        unsigned short tmp[8];
#pragma unroll
        for (int j = 0; j < 8; ++j) tmp[j] = f2bf(pb[j]);
        *(s16x8*)&Bs[bn][bkg * 8] = *(s16x8*)tmp;
    };
    auto mmaT = [&]() {
        s16x8 af[2], bfr[4];
#pragma unroll
        for (int mt = 0; mt < 2; ++mt)
            af[mt] = *(const s16x8*)&As[wm * 32 + mt * 16 + mlane][quad * 8];
#pragma unroll
        for (int nt = 0; nt < 4; ++nt)
            bfr[nt] = *(const s16x8*)&Bs[wn * 64 + nt * 16 + mlane][quad * 8];
#pragma unroll
        for (int mt = 0; mt < 2; ++mt)
#pragma unroll
            for (int nt = 0; nt < 4; ++nt)
                acc[mt][nt] = __builtin_amdgcn_mfma_f32_16x16x32_bf16(af[mt], bfr[nt], acc[mt][nt], 0, 0, 0);
    };

    // 2-deep pipeline over 16 K-steps (named regs -> no dynamic indexing/scratch)
    loadT(pa0, pb0, 0);
    loadT(pa1, pb1, 32);
    for (int kk = 0; kk < 16; kk += 2) {
        storeT(pa0, pb0);               // waits only on loads issued 2 iters ago
        __syncthreads();
        if (kk + 2 < 16) loadT(pa0, pb0, (kk + 2) * 32);
        mmaT();
        __syncthreads();
        storeT(pa1, pb1);
        __syncthreads();
        if (kk + 3 < 16) loadT(pa1, pb1, (kk + 3) * 32);
        mmaT();
        __syncthreads();
    }

    // epilogue: D[row=quad*4+r][col=lane&15] per frag; scale by dinv(deg), store bf16
#pragma unroll
    for (int mt = 0; mt < 2; ++mt) {
#pragma unroll
        for (int r = 0; r < 4; ++r) {
            int row = bm + wm * 32 + mt * 16 + quad * 4 + r;
            if (row < M) {
                float sc = deg2dinv(deg[row]);
#pragma unroll
                for (int nt = 0; nt < 4; ++nt) {
                    int col = wn * 64 + nt * 16 + mlane;
                    h2[(size_t)row * HH + col] = f2bf(acc[mt][nt][r] * sc);
                }
            }
        }
    }
}

// ---------------- aggregation (bf16 in / bf16 out) ----------------
// agg[d] = bf16( b_conv + dinv[d] * (h2[d] + sum_e w_e * h2[src_e]) )
// one 64-lane wave per node; each lane owns feature pair (2*lane, 2*lane+1) as packed uint.
// Unroll-8 with batched int4 bucket loads: 8 gathers in flight per wave (proven R4).
// [R7 lesson: feature-quartered 16-lane-group variant regressed (intra-wave degree
// divergence + 4x bucket re-reads) — this full-feature layout retained.]

__global__ __launch_bounds__(256) void agg_kernel(const unsigned int* __restrict__ h2u,
                                                  const int* __restrict__ cnt,
                                                  const int2* __restrict__ bucket,
                                                  const float* __restrict__ deg,
                                                  const float* __restrict__ b_conv,
                                                  const int* __restrict__ ovf_cnt,
                                                  const int4* __restrict__ ovf,
                                                  unsigned int* __restrict__ aggu, int n) {
    int idx = blockIdx.x * 256 + threadIdx.x;
    int node = idx >> 6;
    int lane = idx & 63;
    if (node >= n) return;
    int c = min(cnt[node], CAP);
    const int2* e = bucket + (size_t)node * CAP;   // 16B-aligned (node*640)

    unsigned self = h2u[(size_t)node * 64 + lane];
    float a0 = blo(self), a1 = bhi(self);          // acc pair A
    float b0 = 0.0f, b1 = 0.0f;                    // acc pair B (breaks FMA chain)

    int j = 0;
    for (; j + 8 <= c; j += 8) {
        int4 p0 = *(const int4*)(e + j);
        int4 p1 = *(const int4*)(e + j + 2);
        int4 p2 = *(const int4*)(e + j + 4);
        int4 p3 = *(const int4*)(e + j + 6);
        unsigned u0 = h2u[(size_t)p0.x * 64 + lane];
        unsigned u1 = h2u[(size_t)p0.z * 64 + lane];
        unsigned u2 = h2u[(size_t)p1.x * 64 + lane];
        unsigned u3 = h2u[(size_t)p1.z * 64 + lane];
        unsigned u4 = h2u[(size_t)p2.x * 64 + lane];
        unsigned u5 = h2u[(size_t)p2.z * 64 + lane];
        unsigned u6 = h2u[(size_t)p3.x * 64 + lane];
        unsigned u7 = h2u[(size_t)p3.z * 64 + lane];
        float w0 = __int_as_float(p0.y), w1 = __int_as_float(p0.w);
        float w2 = __int_as_float(p1.y), w3 = __int_as_float(p1.w);
        float w4 = __int_as_float(p2.y), w5 = __int_as_float(p2.w);
        float w6 = __int_as_float(p3.y), w7 = __int_as_float(p3.w);
        a0 += w0 * blo(u0); a1 += w0 * bhi(u0);
        b0 += w1 * blo(u1); b1 += w1 * bhi(u1);
        a0 += w2 * blo(u2); a1 += w2 * bhi(u2);
        b0 += w3 * blo(u3); b1 += w3 * bhi(u3);
        a0 += w4 * blo(u4); a1 += w4 * bhi(u4);
        b0 += w5 * blo(u5); b1 += w5 * bhi(u5);
        a0 += w6 * blo(u6); a1 += w6 * bhi(u6);
        b0 += w7 * blo(u7); b1 += w7 * bhi(u7);
    }
    for (; j + 2 <= c; j += 2) {
        int4 p = *(const int4*)(e + j);
        unsigned u0 = h2u[(size_t)p.x * 64 + lane];
        unsigned u1 = h2u[(size_t)p.z * 64 + lane];
        float w0 = __int_as_float(p.y), w1 = __int_as_float(p.w);
        a0 += w0 * blo(u0); a1 += w0 * bhi(u0);
        b0 += w1 * blo(u1); b1 += w1 * bhi(u1);
    }
    if (j < c) {
        int2 p = e[j];
        float w0 = __int_as_float(p.y);
        unsigned u0 = h2u[(size_t)p.x * 64 + lane];
        a0 += w0 * blo(u0); a1 += w0 * bhi(u0);
    }

    // overflow net (ovf_n is ~always 0)
    int ovf_n = min(*ovf_cnt, OVF_CAP);
    for (int i = 0; i < ovf_n; ++i) {
        int4 v = ovf[i];
        if (v.y == node) {
            float w0 = __int_as_float(v.z);
            unsigned u0 = h2u[(size_t)v.x * 64 + lane];
            a0 += w0 * blo(u0); a1 += w0 * bhi(u0);
        }
    }

    float di = deg2dinv(deg[node]);
    float2 bc = *(const float2*)&b_conv[lane * 2];
    float v0 = bc.x + di * (a0 + b0);
    float v1 = bc.y + di * (a1 + b1);
    aggu[(size_t)node * 64 + lane] = (unsigned)f2bf(v0) | ((unsigned)f2bf(v1) << 16);
}

// ---------------- GEMM2: out[M,512](f32) = agg[M,128](bf16) @ Wl[128,512](f32) + b_lin ----
// 512 threads (8 waves, 4x2), 2-deep register prefetch over the 4 K-steps.

__global__ __launch_bounds__(512) void gemm2_kernel(const unsigned short* __restrict__ A,
                                                    const float* __restrict__ B,
                                                    const float* __restrict__ bias,
                                                    float* __restrict__ C,
                                                    int M) {
    __shared__ short As[128][40];
    __shared__ short Bs[128][40];
    const int bm = blockIdx.x * 128;
    const int bnb = blockIdx.y * 128;
    const int tid = threadIdx.x;
    const int wave = tid >> 6, lane = tid & 63;
    const int wm = wave >> 1, wn = wave & 1;        // 4x2 wave grid: 32-row x 64-col per wave
    const int mlane = lane & 15, quad = lane >> 4;

    // staging geometry: A = 512 16B tasks -> 1/thread; B = 512 (n,kg) tasks -> 1/thread
    const int ar = tid >> 2, ach = tid & 3;          // A row, 16B chunk
    const int bn = tid & 127, bkg = tid >> 7;        // B col, k-group (0..3)

    f32x4 acc[2][4];
#pragma unroll
    for (int i = 0; i < 2; ++i)
#pragma unroll
        for (int j = 0; j < 4; ++j) acc[i][j] = (f32x4){0.f, 0.f, 0.f, 0.f};

    s16x8 pa0, pa1;
    float pb0[8], pb1[8];

    auto loadT = [&](s16x8& pa, float (&pb)[8], int k0) {
        int grow = bm + ar;
        pa = (s16x8){0, 0, 0, 0, 0, 0, 0, 0};
        if (grow < M) pa = *(const s16x8*)(A + (size_t)grow * HH + k0 + ach * 8);
#pragma unroll
        for (int j = 0; j < 8; ++j)
            pb[j] = B[(size_t)(k0 + bkg * 8 + j) * FIN + bnb + bn];
    };
    auto storeT = [&](s16x8& pa, float (&pb)[8]) {
        *(s16x8*)&As[ar][ach * 8] = pa;
        unsigned short tmp[8];
#pragma unroll
        for (int j = 0; j < 8; ++j) tmp[j] = f2bf(pb[j]);
        *(s16x8*)&Bs[bn][bkg * 8] = *(s16x8*)tmp;
    };
    auto mmaT = [&]() {
        s16x8 af[2], bfr[4];
#pragma unroll
        for (int mt = 0; mt < 2; ++mt)
            af[mt] = *(const s16x8*)&As[wm * 32 + mt * 16 + mlane][quad * 8];
#pragma unroll
        for (int nt = 0; nt < 4; ++nt)
            bfr[nt] = *(const s16x8*)&Bs[wn * 64 + nt * 16 + mlane][quad * 8];
#pragma unroll
        for (int mt = 0; mt < 2; ++mt)
#pragma unroll
            for (int nt = 0; nt < 4; ++nt)
                acc[mt][nt] = __builtin_amdgcn_mfma_f32_16x16x32_bf16(af[mt], bfr[nt], acc[mt][nt], 0, 0, 0);
    };

    // 2-deep pipeline over 4 K-steps
    loadT(pa0, pb0, 0);
    loadT(pa1, pb1, 32);
    for (int kk = 0; kk < 4; kk += 2) {
        storeT(pa0, pb0);
        __syncthreads();
        if (kk + 2 < 4) loadT(pa0, pb0, (kk + 2) * 32);
        mmaT();
        __syncthreads();
        storeT(pa1, pb1);
        __syncthreads();
        if (kk + 3 < 4) loadT(pa1, pb1, (kk + 3) * 32);
        mmaT();
        __syncthreads();
    }

#pragma unroll
    for (int mt = 0; mt < 2; ++mt) {
#pragma unroll
        for (int r = 0; r < 4; ++r) {
            int row = bm + wm * 32 + mt * 16 + quad * 4 + r;
            if (row < M) {
#pragma unroll
                for (int nt = 0; nt < 4; ++nt) {
                    int col = bnb + wn * 64 + nt * 16 + mlane;
                    C[(size_t)row * FIN + col] = acc[mt][nt][r] + bias[col];
                }
            }
        }
    }
}

// ---------------- launch ----------------

extern "C" void kernel_launch(void* const* d_in, const int* in_sizes, int n_in,
                              void* d_out, int out_size, void* d_ws, size_t ws_size,
                              hipStream_t stream) {
    const float* x      = (const float*)d_in[0];
    const int*   ei     = (const int*)d_in[1];
    const float* ew     = (const float*)d_in[2];
    const float* W_conv = (const float*)d_in[3];
    const float* b_conv = (const float*)d_in[4];
    const float* W_lin  = (const float*)d_in[5];
    const float* b_lin  = (const float*)d_in[6];
    float* out = (float*)d_out;

    const int* src = ei;
    const int* dst = ei + EE;

    // workspace layout (bytes, 256-aligned):
    char* ws = (char*)d_ws;
    int*            cnt      = (int*)           (ws + 0);          //   200,704
    float*          deg      = (float*)         (ws + 200704);     //   200,704
    int*            ovf_cnt  = (int*)           (ws + 602112);     //   4 (block of 256)
    int*            cursor   = (int*)           (ws + 602116);     //   4 (same block)
    int*            binTotal = (int*)           (ws + 602368);     //     1,792
    int*            binBase  = (int*)           (ws + 604160);     //     1,792
    int4*           ovf      = (int4*)          (ws + 605952);     // 1,032,192 (64512 entries) -> 1,638,144
    int2*           bucket   = (int2*)          (ws + 1650944);    // 32,000,000 -> 33,650,944
    unsigned short* h2       = (unsigned short*)(ws + 33650944);   // 12,800,000
    unsigned short* agg      = (unsigned short*)(ws + 46450944);   // 12,800,000
    // end: 59,250,944 bytes (unchanged footprint)

    // hist/off ALIAS the bucket region (dead until bucket_build writes bucket):
    int*            hist     = (int*)           (ws + 1650944);    //   400,640 (256*391*4)
    int*            off      = (int*)           (ws + 2051584);    //   400,640
    // bins ALIASES h2 (dead until gemm1): 1.6M * 8B = 12,800,000 exactly
    int2*           bins     = (int2*)          (ws + 33650944);

    hipMemsetAsync(ovf_cnt, 0, 2 * sizeof(int), stream);   // ovf_cnt + cursor

    const int nb_w = (NN * 64 + 255) / 256;   // one wave per node

    // build: atomic-free counting sort by bin, then per-bin bucket build (LDS atomics)
    hist_kernel<<<NBLK, 256, 0, stream>>>(dst, hist);
    scan_bins<<<NB, 64, 0, stream>>>(hist, off, binTotal, binBase, cursor);
    place_kernel<<<NBLK, 256, 0, stream>>>(src, dst, ew, off, binBase, bins);
    bucket_build<<<NB, 512, 0, stream>>>(binBase, binTotal, bins, cnt, bucket, deg, ovf_cnt, ovf);

    // GEMM1: h2 = bf16(dinv .* (x @ W_conv)), dinv = rsqrt(deg) inline
    gemm1_kernel<<<dim3((NN + 127) / 128, 1), 512, 0, stream>>>(x, W_conv, deg, h2, NN);

    // aggregation (bf16 -> bf16)
    agg_kernel<<<nb_w, 256, 0, stream>>>((const unsigned int*)h2, cnt, bucket, deg, b_conv,
                                         ovf_cnt, ovf, (unsigned int*)agg, NN);

    // GEMM2: out = agg @ W_lin + b_lin
    gemm2_kernel<<<dim3((NN + 127) / 128, FIN / 128), 512, 0, stream>>>(agg, W_lin, b_lin, out, NN);
}